// Round 3
// baseline (7996.652 us; speedup 1.0000x reference)
//
#include <hip/hip_runtime.h>
#include <cstddef>

#define B_    256
#define TSUB  192
#define SEQ_  128
#define D_    768
#define H_    256
#define G_    1024   // 4*H
#define DH_   512    // 2*H

typedef __attribute__((ext_vector_type(4))) float f32x4;
typedef __attribute__((ext_vector_type(8))) short bf16x8;

__device__ __forceinline__ float sigf_(float x)  { return 1.0f / (1.0f + __expf(-x)); }
__device__ __forceinline__ float tanhf_(float x) { return 1.0f - 2.0f / (__expf(2.0f * x) + 1.0f); }

__device__ __forceinline__ unsigned short f2bf_(float x) {
    unsigned u = __builtin_bit_cast(unsigned, x);
    return (unsigned short)((u + 0x7fffu + ((u >> 16) & 1u)) >> 16);
}

// ---------------------------------------------------------------------------
// Kernel 1: scatter-average.  One block per batch element.
// ---------------------------------------------------------------------------
__global__ __launch_bounds__(256) void scatter_avg_kernel(
    const float* __restrict__ emb, const int* __restrict__ wid,
    float* __restrict__ avg)
{
    const int b   = blockIdx.x;
    const int tid = threadIdx.x;
    __shared__ int s_wid[TSUB];
    __shared__ int s_start[SEQ_ + 1];

    for (int i = tid; i < TSUB; i += 256) s_wid[i] = wid[b * TSUB + i];
    __syncthreads();
    for (int s = tid; s <= SEQ_; s += 256) {
        int cnt = 0;
        for (int t = 0; t < TSUB; ++t) cnt += (s_wid[t] < s) ? 1 : 0;
        s_start[s] = cnt;
    }
    __syncthreads();

    const float* eb = emb + (size_t)b * TSUB * D_;
    float*       ab = avg + (size_t)b * SEQ_ * D_;
    for (int s = 0; s < SEQ_; ++s) {
        const int st = s_start[s], en = s_start[s + 1];
        const float inv = (en > st) ? 1.0f / (float)(en - st) : 0.0f;
        for (int d = tid; d < D_; d += 256) {
            float sum = 0.0f;
            for (int t = st; t < en; ++t) sum += eb[(size_t)t * D_ + d];
            ab[(size_t)s * D_ + d] = sum * inv;
        }
    }
}

// ---------------------------------------------------------------------------
// Kernel 2: swizzle the four w_hh (1024x256 f32) into bf16 MFMA B-fragment
// lane order.  Per matrix: [wave w(8)][kt(8)][frag f=g*2+jt(8)][lane(64)][j(8)]
//   n = g*256 + w*32 + jt*16 + (lane&15)   (w_hh row: gate-major)
//   k = kt*32 + (lane>>4)*8 + j
// So in the LSTM, each B-fragment is ONE coalesced 16B/lane global load.
// ---------------------------------------------------------------------------
__global__ __launch_bounds__(256) void wswz_kernel(
    const float* __restrict__ w0, const float* __restrict__ w1,
    const float* __restrict__ w2, const float* __restrict__ w3,
    short* __restrict__ out)
{
    const int idx  = blockIdx.x * 256 + threadIdx.x;    // 4*262144
    const int mat  = idx >> 18;
    const int i2   = idx & 262143;
    const int j    = i2 & 7;
    const int l    = (i2 >> 3) & 63;
    const int f    = (i2 >> 9) & 7;
    const int kt   = (i2 >> 12) & 7;
    const int wv   = i2 >> 15;
    const int g    = f >> 1, jt = f & 1;
    const int n    = g * 256 + wv * 32 + jt * 16 + (l & 15);
    const int k    = kt * 32 + (l >> 4) * 8 + j;
    const float* w = (mat == 0) ? w0 : (mat == 1) ? w1 : (mat == 2) ? w2 : w3;
    out[idx] = (short)f2bf_(w[n * H_ + k]);
}

// ---------------------------------------------------------------------------
// Kernel 3: f32 tiled GEMM  C[M,N] = act( X[M,K] @ W[N,K]^T + bias1 + bias2 )
// ---------------------------------------------------------------------------
__global__ __launch_bounds__(256) void gemm_bt_kernel(
    const float* __restrict__ X, const float* __restrict__ W,
    const float* __restrict__ bias1, const float* __restrict__ bias2,
    float* __restrict__ C, int M, int N, int K, int relu)
{
    __shared__ float Xs[16][65];
    __shared__ float Ws[16][65];
    const int m0  = blockIdx.x * 64;
    const int n0  = blockIdx.y * 64;
    const int tid = threadIdx.x;
    const int tx  = tid & 15, ty = tid >> 4;

    float acc[4][4];
#pragma unroll
    for (int i = 0; i < 4; ++i)
#pragma unroll
        for (int j = 0; j < 4; ++j) acc[i][j] = 0.0f;

    for (int k0 = 0; k0 < K; k0 += 16) {
#pragma unroll
        for (int l = 0; l < 4; ++l) {
            const int e = l * 256 + tid;
            const int r = e >> 4, k = e & 15;
            Xs[k][r] = X[(size_t)(m0 + r) * K + k0 + k];
            Ws[k][r] = W[(size_t)(n0 + r) * K + k0 + k];
        }
        __syncthreads();
#pragma unroll
        for (int kk = 0; kk < 16; ++kk) {
            float a[4], bv[4];
#pragma unroll
            for (int i = 0; i < 4; ++i) a[i] = Xs[kk][ty * 4 + i];
#pragma unroll
            for (int j = 0; j < 4; ++j) bv[j] = Ws[kk][tx * 4 + j];
#pragma unroll
            for (int i = 0; i < 4; ++i)
#pragma unroll
                for (int j = 0; j < 4; ++j) acc[i][j] += a[i] * bv[j];
        }
        __syncthreads();
    }

#pragma unroll
    for (int i = 0; i < 4; ++i) {
        const int m = m0 + ty * 4 + i;
#pragma unroll
        for (int j = 0; j < 4; ++j) {
            const int n = n0 + tx * 4 + j;
            float v = acc[i][j] + bias1[n] + (bias2 ? bias2[n] : 0.0f);
            if (relu) v = fmaxf(v, 0.0f);
            C[(size_t)m * N + n] = v;
        }
    }
}

// ---------------------------------------------------------------------------
// Kernel 4: persistent bidirectional LSTM layer, bf16 MFMA recurrence.
// 16 blocks = dir(2) x group(8), BB=32 batches/block, 512 threads (8 waves).
// Wave w owns hidden units [32w,32w+32) for ALL 4 gates -> i/f/g/o for a
// (batch,j) are register-local after MFMA (C layout col=l&15,row=4*(l>>4)+r).
// Weights: pre-swizzled bf16 B-frags streamed L2->reg (1 load/frag).
// h: LDS bf16 [m][k] with XOR swizzle (byte ^= (m&7)<<4), A-frags via
// single ds_read_b128.  acc f32 (MFMA), gates/states f32.
// ---------------------------------------------------------------------------
__global__ __launch_bounds__(512, 2) void lstm_kernel(
    const float* __restrict__ xpf, const float* __restrict__ xpb,
    const short* __restrict__ wswf, const short* __restrict__ wswb,
    float* __restrict__ hout)
{
    const int dir  = blockIdx.x >> 3;
    const int grp  = blockIdx.x & 7;
    const int tid  = threadIdx.x;
    const int wv   = tid >> 6;          // wave 0..7
    const int lane = tid & 63;
    const int lm   = lane & 15;
    const int lk   = lane >> 4;
    const float* xp  = dir ? xpb : xpf;
    const short* wsw = dir ? wswb : wswf;
    const int b0 = grp * 32;

    __shared__ short h_lds[32 * 256];   // 16 KB, [m][k] bf16, XOR-swizzled

    // zero init
    for (int i = tid; i < 32 * 256 / 2; i += 512) ((int*)h_lds)[i] = 0;

    f32x4 acc[2][4][2];                 // [mt][gate][jt]
    float c_st[2][2][4];                // [mt][jt][r]
#pragma unroll
    for (int mt = 0; mt < 2; ++mt)
#pragma unroll
        for (int jt = 0; jt < 2; ++jt)
#pragma unroll
            for (int r = 0; r < 4; ++r) c_st[mt][jt][r] = 0.0f;
    __syncthreads();

    for (int step = 0; step < SEQ_; ++step) {
        const int t = dir ? (SEQ_ - 1 - step) : step;

        // acc init from xp (f32, biases already folded in)
#pragma unroll
        for (int mt = 0; mt < 2; ++mt)
#pragma unroll
            for (int g = 0; g < 4; ++g)
#pragma unroll
                for (int jt = 0; jt < 2; ++jt) {
                    const int n = g * 256 + wv * 32 + jt * 16 + lm;
#pragma unroll
                    for (int r = 0; r < 4; ++r) {
                        const int m = mt * 16 + lk * 4 + r;
                        acc[mt][g][jt][r] =
                            xp[((size_t)(b0 + m) * SEQ_ + t) * G_ + n];
                    }
                }

        // K loop: 8 k-tiles of 32
#pragma unroll 2
        for (int kt = 0; kt < 8; ++kt) {
            // B-frags: 8 coalesced 16B/lane loads (pre-swizzled, L2-resident)
            const short* wbase = wsw + ((size_t)(wv * 8 + kt) * 8) * 512 + lane * 8;
            bf16x8 bfr[8];
#pragma unroll
            for (int f = 0; f < 8; ++f)
                bfr[f] = *(const bf16x8*)(wbase + f * 512);
            // A-frags from LDS (XOR-swizzled)
            bf16x8 a[2];
#pragma unroll
            for (int mt = 0; mt < 2; ++mt) {
                const int m  = mt * 16 + lm;
                const int ba = m * 512 + (((kt * 32 + lk * 8) * 2) ^ ((m & 7) << 4));
                a[mt] = *(const bf16x8*)((const char*)h_lds + ba);
            }
#pragma unroll
            for (int f = 0; f < 8; ++f) {
                const int g = f >> 1, jt = f & 1;
#pragma unroll
                for (int mt = 0; mt < 2; ++mt)
                    acc[mt][g][jt] = __builtin_amdgcn_mfma_f32_16x16x32_bf16(
                        a[mt], bfr[f], acc[mt][g][jt], 0, 0, 0);
            }
        }

        __syncthreads();   // all h_lds reads done before overwrite

        // pointwise: gates register-local per lane
#pragma unroll
        for (int mt = 0; mt < 2; ++mt)
#pragma unroll
            for (int jt = 0; jt < 2; ++jt)
#pragma unroll
                for (int r = 0; r < 4; ++r) {
                    const float iv = sigf_(acc[mt][0][jt][r]);
                    const float fv = sigf_(acc[mt][1][jt][r]);
                    const float gv = tanhf_(acc[mt][2][jt][r]);
                    const float ov = sigf_(acc[mt][3][jt][r]);
                    const float c  = fv * c_st[mt][jt][r] + iv * gv;
                    c_st[mt][jt][r] = c;
                    const float h  = ov * tanhf_(c);
                    const int m = mt * 16 + lk * 4 + r;
                    const int j = wv * 32 + jt * 16 + lm;
                    const int ba = m * 512 + ((2 * j) ^ ((m & 7) << 4));
                    *(unsigned short*)((char*)h_lds + ba) = f2bf_(h);
                    hout[((size_t)(b0 + m) * SEQ_ + t) * DH_ + dir * H_ + j] = h;
                }

        __syncthreads();   // new h visible for next step
    }
}

// ---------------------------------------------------------------------------
// Kernel 5: final logits.  out layout: (B, 2, SEQ)
// ---------------------------------------------------------------------------
__global__ __launch_bounds__(256) void logits_kernel(
    const float* __restrict__ ff, const float* __restrict__ w_sbd,
    const float* __restrict__ b_sbd, float* __restrict__ out)
{
    const int wave = threadIdx.x >> 6, lane = threadIdx.x & 63;
    const int row  = blockIdx.x * 4 + wave;
    const int b    = row >> 7, t = row & 127;
    const float* fr = ff + (size_t)row * DH_;
    float a0 = 0.0f, a1 = 0.0f;
    for (int k = lane; k < DH_; k += 64) {
        const float v = fr[k];
        a0 += v * w_sbd[k];
        a1 += v * w_sbd[DH_ + k];
    }
#pragma unroll
    for (int off = 32; off; off >>= 1) {
        a0 += __shfl_down(a0, off);
        a1 += __shfl_down(a1, off);
    }
    if (lane == 0) {
        out[(size_t)b * 2 * SEQ_ + t]        = a0 + b_sbd[0];
        out[(size_t)b * 2 * SEQ_ + SEQ_ + t] = a1 + b_sbd[1];
    }
}

// ---------------------------------------------------------------------------
extern "C" void kernel_launch(void* const* d_in, const int* in_sizes, int n_in,
                              void* d_out, int out_size, void* d_ws, size_t ws_size,
                              hipStream_t stream)
{
    const float* emb   = (const float*)d_in[0];
    const int*   wid   = (const int*)d_in[1];
    const float* w_ih[4] = {(const float*)d_in[2],  (const float*)d_in[6],
                            (const float*)d_in[10], (const float*)d_in[14]};
    const float* w_hh[4] = {(const float*)d_in[3],  (const float*)d_in[7],
                            (const float*)d_in[11], (const float*)d_in[15]};
    const float* b_ih[4] = {(const float*)d_in[4],  (const float*)d_in[8],
                            (const float*)d_in[12], (const float*)d_in[16]};
    const float* b_hh[4] = {(const float*)d_in[5],  (const float*)d_in[9],
                            (const float*)d_in[13], (const float*)d_in[17]};
    const float* w_ff  = (const float*)d_in[18];
    const float* b_ff  = (const float*)d_in[19];
    const float* w_sbd = (const float*)d_in[20];
    const float* b_sbd = (const float*)d_in[21];
    float* out = (float*)d_out;
    float* ws  = (float*)d_ws;

    const size_t OFF_A   = 0;
    const size_t OFF_XPF = 25165824;
    const size_t OFF_XPB = OFF_XPF + 33554432;
    const size_t OFF_WT  = OFF_XPB + 33554432;     // 16B-aligned; 2 MB of bf16 frags
    const size_t OFF_H1  = OFF_WT + 4 * 262144;

    float* avg = ws + OFF_A;
    float* h0  = ws + OFF_A;
    float* ffb = ws + OFF_A;
    float* xpf = ws + OFF_XPF;
    float* xpb = ws + OFF_XPB;
    short* wsw = (short*)(ws + OFF_WT);
    float* h1  = ws + OFF_H1;

    const int M = B_ * SEQ_;

    scatter_avg_kernel<<<B_, 256, 0, stream>>>(emb, wid, avg);
    wswz_kernel<<<4096, 256, 0, stream>>>(w_hh[0], w_hh[1], w_hh[2], w_hh[3], wsw);

    gemm_bt_kernel<<<dim3(M / 64, G_ / 64), 256, 0, stream>>>(
        avg, w_ih[0], b_ih[0], b_hh[0], xpf, M, G_, D_, 0);
    gemm_bt_kernel<<<dim3(M / 64, G_ / 64), 256, 0, stream>>>(
        avg, w_ih[1], b_ih[1], b_hh[1], xpb, M, G_, D_, 0);

    lstm_kernel<<<16, 512, 0, stream>>>(xpf, xpb, wsw, wsw + 262144, h0);

    gemm_bt_kernel<<<dim3(M / 64, G_ / 64), 256, 0, stream>>>(
        h0, w_ih[2], b_ih[2], b_hh[2], xpf, M, G_, DH_, 0);
    gemm_bt_kernel<<<dim3(M / 64, G_ / 64), 256, 0, stream>>>(
        h0, w_ih[3], b_ih[3], b_hh[3], xpb, M, G_, DH_, 0);

    lstm_kernel<<<16, 512, 0, stream>>>(xpf, xpb, wsw + 2 * 262144, wsw + 3 * 262144, h1);

    gemm_bt_kernel<<<dim3(M / 64, DH_ / 64), 256, 0, stream>>>(
        h1, w_ff, b_ff, nullptr, ffb, M, DH_, DH_, 1);

    logits_kernel<<<M / 4, 256, 0, stream>>>(ffb, w_sbd, b_sbd, out);
}

// Round 4
// 7854.541 us; speedup vs baseline: 1.0181x; 1.0181x over previous
//
#include <hip/hip_runtime.h>
#include <cstddef>

#define B_    256
#define TSUB  192
#define SEQ_  128
#define D_    768
#define H_    256
#define G_    1024   // 4*H
#define DH_   512    // 2*H

typedef __attribute__((ext_vector_type(4))) float f32x4;
typedef __attribute__((ext_vector_type(8))) short bf16x8;
typedef __attribute__((ext_vector_type(4))) unsigned short u16x4;

__device__ __forceinline__ float sigf_(float x)  { return 1.0f / (1.0f + __expf(-x)); }
__device__ __forceinline__ float tanhf_(float x) { return 1.0f - 2.0f / (__expf(2.0f * x) + 1.0f); }

__device__ __forceinline__ unsigned short f2bf_(float x) {
    unsigned u = __builtin_bit_cast(unsigned, x);
    return (unsigned short)((u + 0x7fffu + ((u >> 16) & 1u)) >> 16);
}

// ---------------------------------------------------------------------------
// Kernel 1: scatter-average.  One block per batch element.
// ---------------------------------------------------------------------------
__global__ __launch_bounds__(256) void scatter_avg_kernel(
    const float* __restrict__ emb, const int* __restrict__ wid,
    float* __restrict__ avg)
{
    const int b   = blockIdx.x;
    const int tid = threadIdx.x;
    __shared__ int s_wid[TSUB];
    __shared__ int s_start[SEQ_ + 1];

    for (int i = tid; i < TSUB; i += 256) s_wid[i] = wid[b * TSUB + i];
    __syncthreads();
    for (int s = tid; s <= SEQ_; s += 256) {
        int cnt = 0;
        for (int t = 0; t < TSUB; ++t) cnt += (s_wid[t] < s) ? 1 : 0;
        s_start[s] = cnt;
    }
    __syncthreads();

    const float* eb = emb + (size_t)b * TSUB * D_;
    float*       ab = avg + (size_t)b * SEQ_ * D_;
    for (int s = 0; s < SEQ_; ++s) {
        const int st = s_start[s], en = s_start[s + 1];
        const float inv = (en > st) ? 1.0f / (float)(en - st) : 0.0f;
        for (int d = tid; d < D_; d += 256) {
            float sum = 0.0f;
            for (int t = st; t < en; ++t) sum += eb[(size_t)t * D_ + d];
            ab[(size_t)s * D_ + d] = sum * inv;
        }
    }
}

// ---------------------------------------------------------------------------
// Kernel 2: swizzle the four w_hh (1024x256 f32) into bf16 MFMA **A-fragment**
// lane order (weights are the A operand now; batch is the N dim).
// Layout: [mat][wv 16][kt 8][g 4][lane 64][e 8]
//   A[m][k]: m = lane&15 -> hidden row n = g*256 + wv*16 + (lane&15)
//            k = kt*32 + (lane>>4)*8 + e
// In the LSTM each A-fragment is ONE coalesced 16B/lane load.
// ---------------------------------------------------------------------------
__global__ __launch_bounds__(256) void wswz_kernel(
    const float* __restrict__ w0, const float* __restrict__ w1,
    const float* __restrict__ w2, const float* __restrict__ w3,
    short* __restrict__ out)
{
    const int idx  = blockIdx.x * 256 + threadIdx.x;    // 4*262144
    const int mat  = idx >> 18;
    const int i2   = idx & 262143;
    const int e    = i2 & 7;
    const int l    = (i2 >> 3) & 63;
    const int g    = (i2 >> 9) & 3;
    const int kt   = (i2 >> 11) & 7;
    const int wv   = (i2 >> 14) & 15;
    const int n    = g * 256 + wv * 16 + (l & 15);
    const int k    = kt * 32 + ((l >> 4) << 3) + e;
    const float* w = (mat == 0) ? w0 : (mat == 1) ? w1 : (mat == 2) ? w2 : w3;
    out[idx] = (short)f2bf_(w[n * H_ + k]);
}

// ---------------------------------------------------------------------------
// Kernel 3: f32 tiled GEMM  C[M,N] = act( X[M,K] @ W[N,K]^T + bias1 + bias2 )
// ---------------------------------------------------------------------------
__global__ __launch_bounds__(256) void gemm_bt_kernel(
    const float* __restrict__ X, const float* __restrict__ W,
    const float* __restrict__ bias1, const float* __restrict__ bias2,
    float* __restrict__ C, int M, int N, int K, int relu)
{
    __shared__ float Xs[16][65];
    __shared__ float Ws[16][65];
    const int m0  = blockIdx.x * 64;
    const int n0  = blockIdx.y * 64;
    const int tid = threadIdx.x;
    const int tx  = tid & 15, ty = tid >> 4;

    float acc[4][4];
#pragma unroll
    for (int i = 0; i < 4; ++i)
#pragma unroll
        for (int j = 0; j < 4; ++j) acc[i][j] = 0.0f;

    for (int k0 = 0; k0 < K; k0 += 16) {
#pragma unroll
        for (int l = 0; l < 4; ++l) {
            const int e = l * 256 + tid;
            const int r = e >> 4, k = e & 15;
            Xs[k][r] = X[(size_t)(m0 + r) * K + k0 + k];
            Ws[k][r] = W[(size_t)(n0 + r) * K + k0 + k];
        }
        __syncthreads();
#pragma unroll
        for (int kk = 0; kk < 16; ++kk) {
            float a[4], bv[4];
#pragma unroll
            for (int i = 0; i < 4; ++i) a[i] = Xs[kk][ty * 4 + i];
#pragma unroll
            for (int j = 0; j < 4; ++j) bv[j] = Ws[kk][tx * 4 + j];
#pragma unroll
            for (int i = 0; i < 4; ++i)
#pragma unroll
                for (int j = 0; j < 4; ++j) acc[i][j] += a[i] * bv[j];
        }
        __syncthreads();
    }

#pragma unroll
    for (int i = 0; i < 4; ++i) {
        const int m = m0 + ty * 4 + i;
#pragma unroll
        for (int j = 0; j < 4; ++j) {
            const int n = n0 + tx * 4 + j;
            float v = acc[i][j] + bias1[n] + (bias2 ? bias2[n] : 0.0f);
            if (relu) v = fmaxf(v, 0.0f);
            C[(size_t)m * N + n] = v;
        }
    }
}

// ---------------------------------------------------------------------------
// Kernel 4: persistent bidirectional LSTM, bf16 MFMA, SWAPPED operands.
// 16 blocks = dir(2) x grp(8), BB=32 batches/block, 1024 threads = 16 waves
// (4 waves/SIMD).  Wave wv owns hidden units [16wv,16wv+16) for all 4 gates.
// MFMA: A = weights (pre-swizzled, 1 coalesced 16B/lane load per frag),
//       B = h from LDS [b][k] bf16 XOR-swizzled (ds_read_b128),
//       C rows = hidden j (4 consecutive per lane), cols = batch.
// => xp init is f32x4 loads, h LDS write is ds_write_b64, hout is f32x4.
// ---------------------------------------------------------------------------
__global__ __launch_bounds__(1024) void lstm_kernel(
    const float* __restrict__ xpf, const float* __restrict__ xpb,
    const short* __restrict__ wswf, const short* __restrict__ wswb,
    float* __restrict__ hout)
{
    const int dir  = blockIdx.x >> 3;
    const int grp  = blockIdx.x & 7;
    const int tid  = threadIdx.x;
    const int wv   = tid >> 6;          // wave 0..15
    const int lane = tid & 63;
    const int lm   = lane & 15;
    const int lk   = lane >> 4;
    const float* xp  = dir ? xpb : xpf;
    const short* wsw = dir ? wswb : wswf;
    const int b0 = grp * 32;

    __shared__ short h_lds[32 * 256];   // 16 KB, [b][k] bf16, XOR-swizzled

    for (int i = tid; i < 32 * 256 / 2; i += 1024) ((int*)h_lds)[i] = 0;

    float c_st[2][4];
#pragma unroll
    for (int nt = 0; nt < 2; ++nt)
#pragma unroll
        for (int r = 0; r < 4; ++r) c_st[nt][r] = 0.0f;

    const int jbase = wv * 16;          // this wave's hidden slice
    const int j0    = jbase + lk * 4;   // C-row base for this lane
    __syncthreads();

    for (int step = 0; step < SEQ_; ++step) {
        const int t = dir ? (SEQ_ - 1 - step) : step;

        // acc init from xp: one f32x4 per fragment (biases pre-folded)
        f32x4 acc[2][4];
#pragma unroll
        for (int nt = 0; nt < 2; ++nt) {
            const float* xr = xp + ((size_t)(b0 + nt * 16 + lm) * SEQ_ + t) * G_ + j0;
#pragma unroll
            for (int g = 0; g < 4; ++g)
                acc[nt][g] = *(const f32x4*)(xr + g * 256);
        }

        // K loop: 8 k-tiles of 32
#pragma unroll 2
        for (int kt = 0; kt < 8; ++kt) {
            const short* wb = wsw + (((size_t)(wv * 8 + kt) * 4) << 9) + lane * 8;
            bf16x8 aw[4];
#pragma unroll
            for (int g = 0; g < 4; ++g)
                aw[g] = *(const bf16x8*)(wb + (g << 9));
            bf16x8 bh[2];
#pragma unroll
            for (int nt = 0; nt < 2; ++nt) {
                const int b   = nt * 16 + lm;
                const int off = b * 512 + (((kt * 32 + lk * 8) * 2) ^ ((b & 7) << 4));
                bh[nt] = *(const bf16x8*)((const char*)h_lds + off);
            }
#pragma unroll
            for (int g = 0; g < 4; ++g)
#pragma unroll
                for (int nt = 0; nt < 2; ++nt)
                    acc[nt][g] = __builtin_amdgcn_mfma_f32_16x16x32_bf16(
                        aw[g], bh[nt], acc[nt][g], 0, 0, 0);
        }

        __syncthreads();   // all h_lds reads done before overwrite

        // pointwise: i/f/g/o register-local; write h (bf16x4 LDS, f32x4 global)
#pragma unroll
        for (int nt = 0; nt < 2; ++nt) {
            const int b = nt * 16 + lm;
            f32x4 hv;
            u16x4 hb;
#pragma unroll
            for (int r = 0; r < 4; ++r) {
                const float iv = sigf_(acc[nt][0][r]);
                const float fv = sigf_(acc[nt][1][r]);
                const float gv = tanhf_(acc[nt][2][r]);
                const float ov = sigf_(acc[nt][3][r]);
                const float c  = fv * c_st[nt][r] + iv * gv;
                c_st[nt][r] = c;
                const float h  = ov * tanhf_(c);
                hv[r] = h;
                hb[r] = f2bf_(h);
            }
            const int off = b * 512 + ((j0 * 2) ^ ((b & 7) << 4));
            *(u16x4*)((char*)h_lds + off) = hb;
            *(f32x4*)&hout[((size_t)(b0 + b) * SEQ_ + t) * DH_ + dir * H_ + j0] = hv;
        }

        __syncthreads();   // new h visible for next step
    }
}

// ---------------------------------------------------------------------------
// Kernel 5: final logits.  out layout: (B, 2, SEQ)
// ---------------------------------------------------------------------------
__global__ __launch_bounds__(256) void logits_kernel(
    const float* __restrict__ ff, const float* __restrict__ w_sbd,
    const float* __restrict__ b_sbd, float* __restrict__ out)
{
    const int wave = threadIdx.x >> 6, lane = threadIdx.x & 63;
    const int row  = blockIdx.x * 4 + wave;
    const int b    = row >> 7, t = row & 127;
    const float* fr = ff + (size_t)row * DH_;
    float a0 = 0.0f, a1 = 0.0f;
    for (int k = lane; k < DH_; k += 64) {
        const float v = fr[k];
        a0 += v * w_sbd[k];
        a1 += v * w_sbd[DH_ + k];
    }
#pragma unroll
    for (int off = 32; off; off >>= 1) {
        a0 += __shfl_down(a0, off);
        a1 += __shfl_down(a1, off);
    }
    if (lane == 0) {
        out[(size_t)b * 2 * SEQ_ + t]        = a0 + b_sbd[0];
        out[(size_t)b * 2 * SEQ_ + SEQ_ + t] = a1 + b_sbd[1];
    }
}

// ---------------------------------------------------------------------------
extern "C" void kernel_launch(void* const* d_in, const int* in_sizes, int n_in,
                              void* d_out, int out_size, void* d_ws, size_t ws_size,
                              hipStream_t stream)
{
    const float* emb   = (const float*)d_in[0];
    const int*   wid   = (const int*)d_in[1];
    const float* w_ih[4] = {(const float*)d_in[2],  (const float*)d_in[6],
                            (const float*)d_in[10], (const float*)d_in[14]};
    const float* w_hh[4] = {(const float*)d_in[3],  (const float*)d_in[7],
                            (const float*)d_in[11], (const float*)d_in[15]};
    const float* b_ih[4] = {(const float*)d_in[4],  (const float*)d_in[8],
                            (const float*)d_in[12], (const float*)d_in[16]};
    const float* b_hh[4] = {(const float*)d_in[5],  (const float*)d_in[9],
                            (const float*)d_in[13], (const float*)d_in[17]};
    const float* w_ff  = (const float*)d_in[18];
    const float* b_ff  = (const float*)d_in[19];
    const float* w_sbd = (const float*)d_in[20];
    const float* b_sbd = (const float*)d_in[21];
    float* out = (float*)d_out;
    float* ws  = (float*)d_ws;

    const size_t OFF_A   = 0;
    const size_t OFF_XPF = 25165824;
    const size_t OFF_XPB = OFF_XPF + 33554432;
    const size_t OFF_WT  = OFF_XPB + 33554432;
    const size_t OFF_H1  = OFF_WT + 4 * 262144;

    float* avg = ws + OFF_A;
    float* h0  = ws + OFF_A;
    float* ffb = ws + OFF_A;
    float* xpf = ws + OFF_XPF;
    float* xpb = ws + OFF_XPB;
    short* wsw = (short*)(ws + OFF_WT);
    float* h1  = ws + OFF_H1;

    const int M = B_ * SEQ_;

    scatter_avg_kernel<<<B_, 256, 0, stream>>>(emb, wid, avg);
    wswz_kernel<<<4096, 256, 0, stream>>>(w_hh[0], w_hh[1], w_hh[2], w_hh[3], wsw);

    gemm_bt_kernel<<<dim3(M / 64, G_ / 64), 256, 0, stream>>>(
        avg, w_ih[0], b_ih[0], b_hh[0], xpf, M, G_, D_, 0);
    gemm_bt_kernel<<<dim3(M / 64, G_ / 64), 256, 0, stream>>>(
        avg, w_ih[1], b_ih[1], b_hh[1], xpb, M, G_, D_, 0);

    lstm_kernel<<<16, 1024, 0, stream>>>(xpf, xpb, wsw, wsw + 262144, h0);

    gemm_bt_kernel<<<dim3(M / 64, G_ / 64), 256, 0, stream>>>(
        h0, w_ih[2], b_ih[2], b_hh[2], xpf, M, G_, DH_, 0);
    gemm_bt_kernel<<<dim3(M / 64, G_ / 64), 256, 0, stream>>>(
        h0, w_ih[3], b_ih[3], b_hh[3], xpb, M, G_, DH_, 0);

    lstm_kernel<<<16, 1024, 0, stream>>>(xpf, xpb, wsw + 2 * 262144, wsw + 3 * 262144, h1);

    gemm_bt_kernel<<<dim3(M / 64, DH_ / 64), 256, 0, stream>>>(
        h1, w_ff, b_ff, nullptr, ffb, M, DH_, DH_, 1);

    logits_kernel<<<M / 4, 256, 0, stream>>>(ffb, w_sbd, b_sbd, out);
}

// Round 5
// 3500.801 us; speedup vs baseline: 2.2842x; 2.2436x over previous
//
#include <hip/hip_runtime.h>
#include <cstddef>

#define B_    256
#define TSUB  192
#define SEQ_  128
#define D_    768
#define H_    256
#define G_    1024   // 4*H
#define DH_   512    // 2*H

typedef __attribute__((ext_vector_type(4))) float f32x4;
typedef __attribute__((ext_vector_type(8))) short bf16x8;
typedef __attribute__((ext_vector_type(4))) unsigned short u16x4;

__device__ __forceinline__ float sigf_(float x)  { return 1.0f / (1.0f + __expf(-x)); }
__device__ __forceinline__ float tanhf_(float x) { return 1.0f - 2.0f / (__expf(2.0f * x) + 1.0f); }

__device__ __forceinline__ unsigned short f2bf_(float x) {
    unsigned u = __builtin_bit_cast(unsigned, x);
    return (unsigned short)((u + 0x7fffu + ((u >> 16) & 1u)) >> 16);
}
__device__ __forceinline__ float bf2f_(unsigned short h) {
    return __builtin_bit_cast(float, (unsigned)h << 16);
}
__device__ __forceinline__ void gload_lds16(const void* g, void* l) {
    __builtin_amdgcn_global_load_lds(
        (const __attribute__((address_space(1))) unsigned int*)g,
        (__attribute__((address_space(3))) unsigned int*)l, 16, 0, 0);
}

// ---------------------------------------------------------------------------
// Kernel 1: scatter-average.  One block per batch element.
// ---------------------------------------------------------------------------
__global__ __launch_bounds__(256) void scatter_avg_kernel(
    const float* __restrict__ emb, const int* __restrict__ wid,
    float* __restrict__ avg)
{
    const int b   = blockIdx.x;
    const int tid = threadIdx.x;
    __shared__ int s_wid[TSUB];
    __shared__ int s_start[SEQ_ + 1];

    for (int i = tid; i < TSUB; i += 256) s_wid[i] = wid[b * TSUB + i];
    __syncthreads();
    for (int s = tid; s <= SEQ_; s += 256) {
        int cnt = 0;
        for (int t = 0; t < TSUB; ++t) cnt += (s_wid[t] < s) ? 1 : 0;
        s_start[s] = cnt;
    }
    __syncthreads();

    const float* eb = emb + (size_t)b * TSUB * D_;
    float*       ab = avg + (size_t)b * SEQ_ * D_;
    for (int s = 0; s < SEQ_; ++s) {
        const int st = s_start[s], en = s_start[s + 1];
        const float inv = (en > st) ? 1.0f / (float)(en - st) : 0.0f;
        for (int d = tid; d < D_; d += 256) {
            float sum = 0.0f;
            for (int t = st; t < en; ++t) sum += eb[(size_t)t * D_ + d];
            ab[(size_t)s * D_ + d] = sum * inv;
        }
    }
}

// ---------------------------------------------------------------------------
// Kernel 2: in-place split conversion  f32 X[M][K] -> bf16 [M][2K] = [hi|lo].
// One block per row (row staged in LDS, so in-place is race-free).
// ---------------------------------------------------------------------------
__global__ __launch_bounds__(256) void convx_kernel(float* __restrict__ buf, int K)
{
    __shared__ float row[D_];
    float* r = buf + (size_t)blockIdx.x * K;
    const int tid = threadIdx.x;
    for (int k = tid; k < K; k += 256) row[k] = r[k];
    __syncthreads();
    unsigned short* o = (unsigned short*)r;
    for (int k = tid; k < K; k += 256) {
        const float x = row[k];
        const unsigned short hi = f2bf_(x);
        const float lo = x - bf2f_(hi);
        o[k]     = hi;
        o[K + k] = f2bf_(lo);
    }
}

// ---------------------------------------------------------------------------
// Kernel 3: weight split conversion  f32 W[N][K] -> bf16 Wcat[N][3K]=[hi|lo|hi]
// ---------------------------------------------------------------------------
__global__ __launch_bounds__(256) void convw_kernel(
    const float* __restrict__ W, unsigned short* __restrict__ out, int N, int K)
{
    const int idx = blockIdx.x * 256 + threadIdx.x;
    if (idx >= N * K) return;
    const int n = idx / K, k = idx - n * K;
    const float x = W[idx];
    const unsigned short hi = f2bf_(x);
    const float lo = x - bf2f_(hi);
    const size_t ro = (size_t)n * 3 * K;
    out[ro + k]         = hi;
    out[ro + K + k]     = f2bf_(lo);
    out[ro + 2 * K + k] = hi;
}

// ---------------------------------------------------------------------------
// Kernel 4: bf16 MFMA GEMM (m97 structure: 128x128 tile, BK=32, 256 thr,
// global_load_lds width-16, linear LDS).  Computes in split precision:
//   C[M,N] = act( sum over K'=3K of Acat(x)Wcat + b1 (+b2) )
// Acat bf16 [M][2K] = [hi|lo]; Wcat bf16 [N][3K] = [hi|lo|hi].
// k-third 0: Ahi*Whi, 1: Ahi*Wlo, 2: Alo*Whi  (a_kt = kt<KT ? kt : kt-KT).
// ---------------------------------------------------------------------------
__global__ __launch_bounds__(256) void gemm_bf16_kernel(
    const unsigned short* __restrict__ A, const unsigned short* __restrict__ Wc,
    const float* __restrict__ b1, const float* __restrict__ b2,
    float* __restrict__ C, int M, int N, int K, int relu)
{
    const int KT = K >> 5;          // 32-wide tiles per third
    const int NT = 3 * KT;
    const int KA = 2 * K, KW = 3 * K;
    const int n0 = blockIdx.x * 128;
    const int m0 = blockIdx.y * 128;
    const int tid  = threadIdx.x;
    const int wv   = tid >> 6;
    const int lane = tid & 63;
    const int lm   = lane & 15, lk = lane >> 4;
    const int wr   = wv >> 1,   wc = wv & 1;

    __shared__ unsigned short As[128 * 32];   // 8 KB, linear [row][32]
    __shared__ unsigned short Bs[128 * 32];   // 8 KB

    const int srow  = tid >> 2;          // 0..63
    const int scol8 = (tid & 3) * 8;     // halfword col offset

    f32x4 acc[4][4];
#pragma unroll
    for (int i = 0; i < 4; ++i)
#pragma unroll
        for (int j = 0; j < 4; ++j) acc[i][j] = (f32x4){0.f, 0.f, 0.f, 0.f};

    for (int kt = 0; kt < NT; ++kt) {
        const int a_kt = (kt < KT) ? kt : kt - KT;
        const unsigned short* Ag = A  + (size_t)(m0 + srow) * KA + a_kt * 32 + scol8;
        const unsigned short* Bg = Wc + (size_t)(n0 + srow) * KW + kt   * 32 + scol8;
        __syncthreads();   // previous tile fully consumed
        gload_lds16(Ag,                      As + tid * 8);
        gload_lds16(Ag + (size_t)64 * KA,    As + 2048 + tid * 8);
        gload_lds16(Bg,                      Bs + tid * 8);
        gload_lds16(Bg + (size_t)64 * KW,    Bs + 2048 + tid * 8);
        __syncthreads();   // staging complete (compiler drains vmcnt)

        bf16x8 af[4], bfr[4];
#pragma unroll
        for (int mi = 0; mi < 4; ++mi)
            af[mi] = *(const bf16x8*)&As[(wr * 64 + mi * 16 + lm) * 32 + lk * 8];
#pragma unroll
        for (int nj = 0; nj < 4; ++nj)
            bfr[nj] = *(const bf16x8*)&Bs[(wc * 64 + nj * 16 + lm) * 32 + lk * 8];
#pragma unroll
        for (int mi = 0; mi < 4; ++mi)
#pragma unroll
            for (int nj = 0; nj < 4; ++nj)
                acc[mi][nj] = __builtin_amdgcn_mfma_f32_16x16x32_bf16(
                    af[mi], bfr[nj], acc[mi][nj], 0, 0, 0);
    }

#pragma unroll
    for (int mi = 0; mi < 4; ++mi)
#pragma unroll
        for (int nj = 0; nj < 4; ++nj) {
            const int gn = n0 + wc * 64 + nj * 16 + lm;
            const float bias = b1[gn] + (b2 ? b2[gn] : 0.0f);
#pragma unroll
            for (int r = 0; r < 4; ++r) {
                const int gm = m0 + wr * 64 + mi * 16 + lk * 4 + r;
                float v = acc[mi][nj][r] + bias;
                if (relu) v = fmaxf(v, 0.0f);
                C[(size_t)gm * N + gn] = v;
            }
        }
}

// ---------------------------------------------------------------------------
// Kernel 5: swizzle the four w_hh (1024x256 f32) into bf16 MFMA A-fragment
// lane order.  [mat][wv 16][kt 8][g 4][lane 64][e 8]
//   n = g*256 + wv*16 + (lane&15),  k = kt*32 + (lane>>4)*8 + e
// ---------------------------------------------------------------------------
__global__ __launch_bounds__(256) void wswz_kernel(
    const float* __restrict__ w0, const float* __restrict__ w1,
    const float* __restrict__ w2, const float* __restrict__ w3,
    short* __restrict__ out)
{
    const int idx  = blockIdx.x * 256 + threadIdx.x;    // 4*262144
    const int mat  = idx >> 18;
    const int i2   = idx & 262143;
    const int e    = i2 & 7;
    const int l    = (i2 >> 3) & 63;
    const int g    = (i2 >> 9) & 3;
    const int kt   = (i2 >> 11) & 7;
    const int wv   = (i2 >> 14) & 15;
    const int n    = g * 256 + wv * 16 + (l & 15);
    const int k    = kt * 32 + ((l >> 4) << 3) + e;
    const float* w = (mat == 0) ? w0 : (mat == 1) ? w1 : (mat == 2) ? w2 : w3;
    out[idx] = (short)f2bf_(w[n * H_ + k]);
}

// ---------------------------------------------------------------------------
// Kernel 6: persistent bidirectional LSTM, bf16 MFMA (swapped operands).
// 32 blocks = dir(2) x grp(16), BB=16 batches/block, 1024 threads = 16 waves.
// Wave wv owns hidden units [16wv,16wv+16) x 4 gates; batch = N columns.
// xp prefetched one step ahead (hides HBM latency under K-loop+pointwise).
// ---------------------------------------------------------------------------
__global__ __launch_bounds__(1024) void lstm_kernel(
    const float* __restrict__ xpf, const float* __restrict__ xpb,
    const short* __restrict__ wswf, const short* __restrict__ wswb,
    float* __restrict__ hout)
{
    const int dir  = blockIdx.x >> 4;
    const int grp  = blockIdx.x & 15;
    const int tid  = threadIdx.x;
    const int wv   = tid >> 6;          // wave 0..15
    const int lane = tid & 63;
    const int lm   = lane & 15;
    const int lk   = lane >> 4;
    const float* xp  = dir ? xpb : xpf;
    const short* wsw = dir ? wswb : wswf;
    const int b0 = grp * 16;

    __shared__ short h_lds[16 * 256];   // 8 KB, [b][k] bf16, XOR-swizzled

    for (int i = tid; i < 16 * 256 / 2; i += 1024) ((int*)h_lds)[i] = 0;

    float c_st[4];
#pragma unroll
    for (int r = 0; r < 4; ++r) c_st[r] = 0.0f;

    const int j0 = wv * 16 + lk * 4;    // C-row base for this lane
    const int b  = lm;                  // this lane's batch column
    __syncthreads();

    // prefetch xp for step 0
    f32x4 xpre[4];
    {
        const int t0 = dir ? (SEQ_ - 1) : 0;
        const float* xr = xp + ((size_t)(b0 + b) * SEQ_ + t0) * G_ + j0;
#pragma unroll
        for (int g = 0; g < 4; ++g) xpre[g] = *(const f32x4*)(xr + g * 256);
    }

    for (int step = 0; step < SEQ_; ++step) {
        const int t = dir ? (SEQ_ - 1 - step) : step;

        f32x4 acc[4];
#pragma unroll
        for (int g = 0; g < 4; ++g) acc[g] = xpre[g];

        // issue next-step xp loads (latency hidden under K-loop + pointwise)
        {
            const int tn = dir ? (t > 0 ? t - 1 : 0) : (t < SEQ_ - 1 ? t + 1 : t);
            const float* xr = xp + ((size_t)(b0 + b) * SEQ_ + tn) * G_ + j0;
#pragma unroll
            for (int g = 0; g < 4; ++g) xpre[g] = *(const f32x4*)(xr + g * 256);
        }

        // K loop: 8 k-tiles of 32
#pragma unroll 2
        for (int kt = 0; kt < 8; ++kt) {
            const short* wb = wsw + (((size_t)(wv * 8 + kt) * 4) << 9) + lane * 8;
            bf16x8 aw[4];
#pragma unroll
            for (int g = 0; g < 4; ++g)
                aw[g] = *(const bf16x8*)(wb + (g << 9));
            const int off = b * 512 + (((kt * 32 + lk * 8) * 2) ^ ((b & 7) << 4));
            const bf16x8 bh = *(const bf16x8*)((const char*)h_lds + off);
#pragma unroll
            for (int g = 0; g < 4; ++g)
                acc[g] = __builtin_amdgcn_mfma_f32_16x16x32_bf16(
                    aw[g], bh, acc[g], 0, 0, 0);
        }

        __syncthreads();   // all h_lds reads done before overwrite

        f32x4 hv;
        u16x4 hb;
#pragma unroll
        for (int r = 0; r < 4; ++r) {
            const float iv = sigf_(acc[0][r]);
            const float fv = sigf_(acc[1][r]);
            const float gv = tanhf_(acc[2][r]);
            const float ov = sigf_(acc[3][r]);
            const float c  = fv * c_st[r] + iv * gv;
            c_st[r] = c;
            const float h  = ov * tanhf_(c);
            hv[r] = h;
            hb[r] = f2bf_(h);
        }
        const int off = b * 512 + ((j0 * 2) ^ ((b & 7) << 4));
        *(u16x4*)((char*)h_lds + off) = hb;
        *(f32x4*)&hout[((size_t)(b0 + b) * SEQ_ + t) * DH_ + dir * H_ + j0] = hv;

        __syncthreads();   // new h visible for next step
    }
}

// ---------------------------------------------------------------------------
// Kernel 7: final logits.  out layout: (B, 2, SEQ)
// ---------------------------------------------------------------------------
__global__ __launch_bounds__(256) void logits_kernel(
    const float* __restrict__ ff, const float* __restrict__ w_sbd,
    const float* __restrict__ b_sbd, float* __restrict__ out)
{
    const int wave = threadIdx.x >> 6, lane = threadIdx.x & 63;
    const int row  = blockIdx.x * 4 + wave;
    const int b    = row >> 7, t = row & 127;
    const float* fr = ff + (size_t)row * DH_;
    float a0 = 0.0f, a1 = 0.0f;
    for (int k = lane; k < DH_; k += 64) {
        const float v = fr[k];
        a0 += v * w_sbd[k];
        a1 += v * w_sbd[DH_ + k];
    }
#pragma unroll
    for (int off = 32; off; off >>= 1) {
        a0 += __shfl_down(a0, off);
        a1 += __shfl_down(a1, off);
    }
    if (lane == 0) {
        out[(size_t)b * 2 * SEQ_ + t]        = a0 + b_sbd[0];
        out[(size_t)b * 2 * SEQ_ + SEQ_ + t] = a1 + b_sbd[1];
    }
}

// ---------------------------------------------------------------------------
extern "C" void kernel_launch(void* const* d_in, const int* in_sizes, int n_in,
                              void* d_out, int out_size, void* d_ws, size_t ws_size,
                              hipStream_t stream)
{
    const float* emb   = (const float*)d_in[0];
    const int*   wid   = (const int*)d_in[1];
    const float* w_ih[4] = {(const float*)d_in[2],  (const float*)d_in[6],
                            (const float*)d_in[10], (const float*)d_in[14]};
    const float* w_hh[4] = {(const float*)d_in[3],  (const float*)d_in[7],
                            (const float*)d_in[11], (const float*)d_in[15]};
    const float* b_ih[4] = {(const float*)d_in[4],  (const float*)d_in[8],
                            (const float*)d_in[12], (const float*)d_in[16]};
    const float* b_hh[4] = {(const float*)d_in[5],  (const float*)d_in[9],
                            (const float*)d_in[13], (const float*)d_in[17]};
    const float* w_ff  = (const float*)d_in[18];
    const float* b_ff  = (const float*)d_in[19];
    const float* w_sbd = (const float*)d_in[20];
    const float* b_sbd = (const float*)d_in[21];
    float* out = (float*)d_out;
    char*  ws  = (char*)d_ws;

    const int M = B_ * SEQ_;   // 32768

    // ---- workspace layout (bytes) -----------------------------------------
    // R1: avg(f32 M*768) -> in-place Acat0 -> h0(f32) -> Acat1 -> h1 -> Acat2
    const size_t OFF_R1  = 0;                       // 100,663,296 B
    const size_t OFF_XPF = 100663296;               // 134,217,728 B (also ffb)
    const size_t OFF_XPB = OFF_XPF + 134217728;     // 134,217,728 B
    const size_t OFF_WC  = OFF_XPB + 134217728;     // Wcat pool 17,301,504 B
    const size_t OFF_WSW = OFF_WC + 17301504;       // 2,097,152 B
    // total ~389 MB

    float* avg  = (float*)(ws + OFF_R1);
    unsigned short* Acat = (unsigned short*)(ws + OFF_R1);
    float* xpf  = (float*)(ws + OFF_XPF);
    float* xpb  = (float*)(ws + OFF_XPB);
    float* ffb  = (float*)(ws + OFF_XPF);           // reuses xpf after lstm1
    unsigned short* Wc0f = (unsigned short*)(ws + OFF_WC);                  // 1024x2304
    unsigned short* Wc0b = Wc0f + (size_t)1024 * 2304;
    unsigned short* Wc1f = Wc0b + (size_t)1024 * 2304;                      // 1024x1536
    unsigned short* Wc1b = Wc1f + (size_t)1024 * 1536;
    unsigned short* Wcff = Wc1b + (size_t)1024 * 1536;                      // 512x1536
    short* wsw  = (short*)(ws + OFF_WSW);

    // ---- weight conversions (independent of data path) ---------------------
    wswz_kernel<<<4096, 256, 0, stream>>>(w_hh[0], w_hh[1], w_hh[2], w_hh[3], wsw);
    convw_kernel<<<(1024 * 768 + 255) / 256, 256, 0, stream>>>(w_ih[0], Wc0f, 1024, 768);
    convw_kernel<<<(1024 * 768 + 255) / 256, 256, 0, stream>>>(w_ih[1], Wc0b, 1024, 768);
    convw_kernel<<<(1024 * 512 + 255) / 256, 256, 0, stream>>>(w_ih[2], Wc1f, 1024, 512);
    convw_kernel<<<(1024 * 512 + 255) / 256, 256, 0, stream>>>(w_ih[3], Wc1b, 1024, 512);
    convw_kernel<<<(512 * 512 + 255) / 256, 256, 0, stream>>>(w_ff, Wcff, 512, 512);

    // ---- data path ----------------------------------------------------------
    scatter_avg_kernel<<<B_, 256, 0, stream>>>(emb, wid, avg);
    convx_kernel<<<M, 256, 0, stream>>>(avg, D_);                 // avg -> Acat0

    gemm_bf16_kernel<<<dim3(G_ / 128, M / 128), 256, 0, stream>>>(
        Acat, Wc0f, b_ih[0], b_hh[0], xpf, M, G_, D_, 0);
    gemm_bf16_kernel<<<dim3(G_ / 128, M / 128), 256, 0, stream>>>(
        Acat, Wc0b, b_ih[1], b_hh[1], xpb, M, G_, D_, 0);

    lstm_kernel<<<32, 1024, 0, stream>>>(xpf, xpb, wsw, wsw + 262144,
                                         (float*)(ws + OFF_R1));  // h0 -> R1

    convx_kernel<<<M, 256, 0, stream>>>((float*)(ws + OFF_R1), DH_);  // h0 -> Acat1

    gemm_bf16_kernel<<<dim3(G_ / 128, M / 128), 256, 0, stream>>>(
        Acat, Wc1f, b_ih[2], b_hh[2], xpf, M, G_, DH_, 0);
    gemm_bf16_kernel<<<dim3(G_ / 128, M / 128), 256, 0, stream>>>(
        Acat, Wc1b, b_ih[3], b_hh[3], xpb, M, G_, DH_, 0);

    lstm_kernel<<<32, 1024, 0, stream>>>(xpf, xpb, wsw + 2 * 262144, wsw + 3 * 262144,
                                         (float*)(ws + OFF_R1));  // h1 -> R1

    convx_kernel<<<M, 256, 0, stream>>>((float*)(ws + OFF_R1), DH_);  // h1 -> Acat2

    gemm_bf16_kernel<<<dim3(DH_ / 128, M / 128), 256, 0, stream>>>(
        Acat, Wcff, b_ff, nullptr, ffb, M, DH_, DH_, 1);

    logits_kernel<<<M / 4, 256, 0, stream>>>(ffb, w_sbd, b_sbd, out);
}

// Round 6
// 2560.667 us; speedup vs baseline: 3.1229x; 1.3671x over previous
//
#include <hip/hip_runtime.h>
#include <cstddef>

#define B_    256
#define TSUB  192
#define SEQ_  128
#define D_    768
#define H_    256
#define G_    1024   // 4*H
#define DH_   512    // 2*H

typedef __attribute__((ext_vector_type(4))) float f32x4;
typedef __attribute__((ext_vector_type(8))) short bf16x8;
typedef __attribute__((ext_vector_type(4))) unsigned short u16x4;

__device__ __forceinline__ float sigf_(float x)  { return 1.0f / (1.0f + __expf(-x)); }
__device__ __forceinline__ float tanhf_(float x) { return 1.0f - 2.0f / (__expf(2.0f * x) + 1.0f); }

__device__ __forceinline__ unsigned short f2bf_(float x) {
    unsigned u = __builtin_bit_cast(unsigned, x);
    return (unsigned short)((u + 0x7fffu + ((u >> 16) & 1u)) >> 16);
}
__device__ __forceinline__ float bf2f_(unsigned short h) {
    return __builtin_bit_cast(float, (unsigned)h << 16);
}
__device__ __forceinline__ void gload_lds16(const void* g, void* l) {
    __builtin_amdgcn_global_load_lds(
        (const __attribute__((address_space(1))) unsigned int*)g,
        (__attribute__((address_space(3))) unsigned int*)l, 16, 0, 0);
}

// ---------------------------------------------------------------------------
// Kernel 1: scatter-average.  One block per batch element.
// ---------------------------------------------------------------------------
__global__ __launch_bounds__(256) void scatter_avg_kernel(
    const float* __restrict__ emb, const int* __restrict__ wid,
    float* __restrict__ avg)
{
    const int b   = blockIdx.x;
    const int tid = threadIdx.x;
    __shared__ int s_wid[TSUB];
    __shared__ int s_start[SEQ_ + 1];

    for (int i = tid; i < TSUB; i += 256) s_wid[i] = wid[b * TSUB + i];
    __syncthreads();
    for (int s = tid; s <= SEQ_; s += 256) {
        int cnt = 0;
        for (int t = 0; t < TSUB; ++t) cnt += (s_wid[t] < s) ? 1 : 0;
        s_start[s] = cnt;
    }
    __syncthreads();

    const float* eb = emb + (size_t)b * TSUB * D_;
    float*       ab = avg + (size_t)b * SEQ_ * D_;
    for (int s = 0; s < SEQ_; ++s) {
        const int st = s_start[s], en = s_start[s + 1];
        const float inv = (en > st) ? 1.0f / (float)(en - st) : 0.0f;
        for (int d = tid; d < D_; d += 256) {
            float sum = 0.0f;
            for (int t = st; t < en; ++t) sum += eb[(size_t)t * D_ + d];
            ab[(size_t)s * D_ + d] = sum * inv;
        }
    }
}

// ---------------------------------------------------------------------------
// Kernel 2: in-place split conversion  f32 X[M][K] -> bf16 [M][2K] = [hi|lo].
// ---------------------------------------------------------------------------
__global__ __launch_bounds__(256) void convx_kernel(float* __restrict__ buf, int K)
{
    __shared__ float row[D_];
    float* r = buf + (size_t)blockIdx.x * K;
    const int tid = threadIdx.x;
    for (int k = tid; k < K; k += 256) row[k] = r[k];
    __syncthreads();
    unsigned short* o = (unsigned short*)r;
    for (int k = tid; k < K; k += 256) {
        const float x = row[k];
        const unsigned short hi = f2bf_(x);
        const float lo = x - bf2f_(hi);
        o[k]     = hi;
        o[K + k] = f2bf_(lo);
    }
}

// ---------------------------------------------------------------------------
// Kernel 3: weight split conversion  f32 W[N][K] -> bf16 Wcat[N][3K]=[hi|lo|hi]
// ---------------------------------------------------------------------------
__global__ __launch_bounds__(256) void convw_kernel(
    const float* __restrict__ W, unsigned short* __restrict__ out, int N, int K)
{
    const int idx = blockIdx.x * 256 + threadIdx.x;
    if (idx >= N * K) return;
    const int n = idx / K, k = idx - n * K;
    const float x = W[idx];
    const unsigned short hi = f2bf_(x);
    const float lo = x - bf2f_(hi);
    const size_t ro = (size_t)n * 3 * K;
    out[ro + k]         = hi;
    out[ro + K + k]     = f2bf_(lo);
    out[ro + 2 * K + k] = hi;
}

// ---------------------------------------------------------------------------
// Kernel 4: bf16 MFMA GEMM (128x128 tile, BK=32, global_load_lds width-16).
// Split precision: C = act( Acat[M][2K]{hi|lo} x Wcat[N][3K]{hi|lo|hi} + b ).
// ---------------------------------------------------------------------------
__global__ __launch_bounds__(256) void gemm_bf16_kernel(
    const unsigned short* __restrict__ A, const unsigned short* __restrict__ Wc,
    const float* __restrict__ b1, const float* __restrict__ b2,
    float* __restrict__ C, int M, int N, int K, int relu)
{
    const int KT = K >> 5;
    const int NT = 3 * KT;
    const int KA = 2 * K, KW = 3 * K;
    const int n0 = blockIdx.x * 128;
    const int m0 = blockIdx.y * 128;
    const int tid  = threadIdx.x;
    const int wv   = tid >> 6;
    const int lane = tid & 63;
    const int lm   = lane & 15, lk = lane >> 4;
    const int wr   = wv >> 1,   wc = wv & 1;

    __shared__ unsigned short As[128 * 32];
    __shared__ unsigned short Bs[128 * 32];

    const int srow  = tid >> 2;
    const int scol8 = (tid & 3) * 8;

    f32x4 acc[4][4];
#pragma unroll
    for (int i = 0; i < 4; ++i)
#pragma unroll
        for (int j = 0; j < 4; ++j) acc[i][j] = (f32x4){0.f, 0.f, 0.f, 0.f};

    for (int kt = 0; kt < NT; ++kt) {
        const int a_kt = (kt < KT) ? kt : kt - KT;
        const unsigned short* Ag = A  + (size_t)(m0 + srow) * KA + a_kt * 32 + scol8;
        const unsigned short* Bg = Wc + (size_t)(n0 + srow) * KW + kt   * 32 + scol8;
        __syncthreads();
        gload_lds16(Ag,                      As + tid * 8);
        gload_lds16(Ag + (size_t)64 * KA,    As + 2048 + tid * 8);
        gload_lds16(Bg,                      Bs + tid * 8);
        gload_lds16(Bg + (size_t)64 * KW,    Bs + 2048 + tid * 8);
        __syncthreads();

        bf16x8 af[4], bfr[4];
#pragma unroll
        for (int mi = 0; mi < 4; ++mi)
            af[mi] = *(const bf16x8*)&As[(wr * 64 + mi * 16 + lm) * 32 + lk * 8];
#pragma unroll
        for (int nj = 0; nj < 4; ++nj)
            bfr[nj] = *(const bf16x8*)&Bs[(wc * 64 + nj * 16 + lm) * 32 + lk * 8];
#pragma unroll
        for (int mi = 0; mi < 4; ++mi)
#pragma unroll
            for (int nj = 0; nj < 4; ++nj)
                acc[mi][nj] = __builtin_amdgcn_mfma_f32_16x16x32_bf16(
                    af[mi], bfr[nj], acc[mi][nj], 0, 0, 0);
    }

#pragma unroll
    for (int mi = 0; mi < 4; ++mi)
#pragma unroll
        for (int nj = 0; nj < 4; ++nj) {
            const int gn = n0 + wc * 64 + nj * 16 + lm;
            const float bias = b1[gn] + (b2 ? b2[gn] : 0.0f);
#pragma unroll
            for (int r = 0; r < 4; ++r) {
                const int gm = m0 + wr * 64 + mi * 16 + lk * 4 + r;
                float v = acc[mi][nj][r] + bias;
                if (relu) v = fmaxf(v, 0.0f);
                C[(size_t)gm * N + gn] = v;
            }
        }
}

// ---------------------------------------------------------------------------
// Kernel 5: swizzle four w_hh (1024x256 f32) into bf16 MFMA A-fragment order
// for the 8-wave LSTM.  [mat][wv 8][kt 8][fr 8][lane 64][e 8]
//   fr = g*2+s:  n = g*256 + wv*32 + s*16 + (lane&15)
//   k  = kt*32 + (lane>>4)*8 + e
// Each fragment = one coalesced 16B/lane load (or global_load_lds).
// ---------------------------------------------------------------------------
__global__ __launch_bounds__(256) void wswz_kernel(
    const float* __restrict__ w0, const float* __restrict__ w1,
    const float* __restrict__ w2, const float* __restrict__ w3,
    short* __restrict__ out)
{
    const int idx  = blockIdx.x * 256 + threadIdx.x;    // 4*262144
    const int mat  = idx >> 18;
    const int i2   = idx & 262143;
    const int e    = i2 & 7;
    const int l    = (i2 >> 3) & 63;
    const int fr   = (i2 >> 9) & 7;
    const int kt   = (i2 >> 12) & 7;
    const int wv   = (i2 >> 15) & 7;
    const int g    = fr >> 1, s = fr & 1;
    const int n    = g * 256 + wv * 32 + s * 16 + (l & 15);
    const int k    = kt * 32 + ((l >> 4) << 3) + e;
    const float* w = (mat == 0) ? w0 : (mat == 1) ? w1 : (mat == 2) ? w2 : w3;
    out[idx] = (short)f2bf_(w[n * H_ + k]);
}

// ---------------------------------------------------------------------------
// Kernel 6: persistent bidirectional LSTM, bf16 MFMA, WEIGHT-RESIDENT.
// 32 blocks = dir(2) x grp(16), 512 threads = 8 waves (2/SIMD, 256 VGPR cap).
// Wave wv owns j in [32wv,32wv+32) x 4 gates = 64 A-frags (64 KB):
//   kt 0..3  -> registers (32 frags, 128 VGPR)
//   kt 4..5  -> LDS (16 frags/wave, 128 KB/block, staged once)
//   kt 6..7  -> streamed from L2 each step (128 KB/block/step)
// B = h from LDS [b][k] bf16 XOR-swizzled; C rows = gate-rows, cols = batch.
// ---------------------------------------------------------------------------
__global__ __launch_bounds__(512, 2) void lstm_kernel(
    const float* __restrict__ xpf, const float* __restrict__ xpb,
    const short* __restrict__ wswf, const short* __restrict__ wswb,
    float* __restrict__ hout)
{
    const int dir  = blockIdx.x >> 4;
    const int grp  = blockIdx.x & 15;
    const int tid  = threadIdx.x;
    const int wv   = tid >> 6;          // wave 0..7
    const int lane = tid & 63;
    const int lm   = lane & 15;
    const int lk   = lane >> 4;
    const float* xp  = dir ? xpb : xpf;
    const short* wsw = dir ? wswb : wswf;
    const int b0 = grp * 16;
    const int b  = lm;                  // this lane's batch column

    __shared__ short lds_w[65536];      // 128 KB: [wv 8][kt2 2][fr 8][512]
    __shared__ short h_lds[16 * 256];   // 8 KB, [b][k] bf16, XOR-swizzled

    // ---- one-time staging --------------------------------------------------
    // h := 0
    for (int i = tid; i < 16 * 256 / 2; i += 512) ((int*)h_lds)[i] = 0;
    // weights kt 4..5 -> LDS (global_load_lds: dst uniform base + lane*16)
#pragma unroll
    for (int kt2 = 0; kt2 < 2; ++kt2)
#pragma unroll
        for (int fr = 0; fr < 8; ++fr) {
            const short* src = wsw + (((wv * 8 + 4 + kt2) * 8 + fr) << 9) + lane * 8;
            gload_lds16(src, &lds_w[((wv * 2 + kt2) * 8 + fr) << 9]);
        }
    // weights kt 0..3 -> registers (32 frags = 128 VGPR)
    bf16x8 awr[4][8];
#pragma unroll
    for (int kt = 0; kt < 4; ++kt)
#pragma unroll
        for (int fr = 0; fr < 8; ++fr)
            awr[kt][fr] = *(const bf16x8*)(wsw + (((wv * 8 + kt) * 8 + fr) << 9) + lane * 8);

    float c_st[2][4];
#pragma unroll
    for (int s = 0; s < 2; ++s)
#pragma unroll
        for (int r = 0; r < 4; ++r) c_st[s][r] = 0.0f;

    // xp column offsets for the 8 C-fragments of this lane
    int nof[8];
#pragma unroll
    for (int fr = 0; fr < 8; ++fr)
        nof[fr] = (fr >> 1) * 256 + wv * 32 + (fr & 1) * 16 + lk * 4;

    __syncthreads();   // staging complete (vmcnt drained before barrier)

    // prefetch xp for step 0
    f32x4 xpre[8];
    {
        const int t0 = dir ? (SEQ_ - 1) : 0;
        const float* xr = xp + ((size_t)(b0 + b) * SEQ_ + t0) * G_;
#pragma unroll
        for (int fr = 0; fr < 8; ++fr) xpre[fr] = *(const f32x4*)(xr + nof[fr]);
    }

    for (int step = 0; step < SEQ_; ++step) {
        const int t = dir ? (SEQ_ - 1 - step) : step;

        f32x4 acc[8];
#pragma unroll
        for (int fr = 0; fr < 8; ++fr) acc[fr] = xpre[fr];

        // issue streamed kt=6 loads now (consumed ~2000 cyc later)
        bf16x8 aws6[8];
#pragma unroll
        for (int fr = 0; fr < 8; ++fr)
            aws6[fr] = *(const bf16x8*)(wsw + (((wv * 8 + 6) * 8 + fr) << 9) + lane * 8);

        // kt 0..3: register-resident weights
#pragma unroll
        for (int kt = 0; kt < 4; ++kt) {
            const int off = b * 512 + (((kt * 32 + lk * 8) * 2) ^ ((b & 7) << 4));
            const bf16x8 bh = *(const bf16x8*)((const char*)h_lds + off);
#pragma unroll
            for (int fr = 0; fr < 8; ++fr)
                acc[fr] = __builtin_amdgcn_mfma_f32_16x16x32_bf16(
                    awr[kt][fr], bh, acc[fr], 0, 0, 0);
        }

        // kt 4..5: LDS-resident weights
#pragma unroll
        for (int kt2 = 0; kt2 < 2; ++kt2) {
            const int kt = 4 + kt2;
            const int off = b * 512 + (((kt * 32 + lk * 8) * 2) ^ ((b & 7) << 4));
            const bf16x8 bh = *(const bf16x8*)((const char*)h_lds + off);
            bf16x8 al[8];
#pragma unroll
            for (int fr = 0; fr < 8; ++fr)
                al[fr] = *(const bf16x8*)&lds_w[(((wv * 2 + kt2) * 8 + fr) << 9) + lane * 8];
#pragma unroll
            for (int fr = 0; fr < 8; ++fr)
                acc[fr] = __builtin_amdgcn_mfma_f32_16x16x32_bf16(
                    al[fr], bh, acc[fr], 0, 0, 0);
        }

        // issue streamed kt=7 loads (hidden under kt=6 MFMAs)
        bf16x8 aws7[8];
#pragma unroll
        for (int fr = 0; fr < 8; ++fr)
            aws7[fr] = *(const bf16x8*)(wsw + (((wv * 8 + 7) * 8 + fr) << 9) + lane * 8);

        // kt 6
        {
            const int off = b * 512 + (((6 * 32 + lk * 8) * 2) ^ ((b & 7) << 4));
            const bf16x8 bh = *(const bf16x8*)((const char*)h_lds + off);
#pragma unroll
            for (int fr = 0; fr < 8; ++fr)
                acc[fr] = __builtin_amdgcn_mfma_f32_16x16x32_bf16(
                    aws6[fr], bh, acc[fr], 0, 0, 0);
        }
        // kt 7
        {
            const int off = b * 512 + (((7 * 32 + lk * 8) * 2) ^ ((b & 7) << 4));
            const bf16x8 bh = *(const bf16x8*)((const char*)h_lds + off);
#pragma unroll
            for (int fr = 0; fr < 8; ++fr)
                acc[fr] = __builtin_amdgcn_mfma_f32_16x16x32_bf16(
                    aws7[fr], bh, acc[fr], 0, 0, 0);
        }

        __syncthreads();   // all h_lds reads done before overwrite

        // prefetch xp for next step (lands during pointwise + next step head)
        {
            const int tn = dir ? (t > 0 ? t - 1 : 0) : (t < SEQ_ - 1 ? t + 1 : t);
            const float* xr = xp + ((size_t)(b0 + b) * SEQ_ + tn) * G_;
#pragma unroll
            for (int fr = 0; fr < 8; ++fr) xpre[fr] = *(const f32x4*)(xr + nof[fr]);
        }

        // pointwise: fr = g*2+s  ->  i:acc[s], f:acc[2+s], g:acc[4+s], o:acc[6+s]
#pragma unroll
        for (int s = 0; s < 2; ++s) {
            f32x4 hv;
            u16x4 hb;
#pragma unroll
            for (int r = 0; r < 4; ++r) {
                const float iv = sigf_(acc[s][r]);
                const float fv = sigf_(acc[2 + s][r]);
                const float gv = tanhf_(acc[4 + s][r]);
                const float ov = sigf_(acc[6 + s][r]);
                const float c  = fv * c_st[s][r] + iv * gv;
                c_st[s][r] = c;
                const float h  = ov * tanhf_(c);
                hv[r] = h;
                hb[r] = f2bf_(h);
            }
            const int j0  = wv * 32 + s * 16 + lk * 4;
            const int off = b * 512 + ((j0 * 2) ^ ((b & 7) << 4));
            *(u16x4*)((char*)h_lds + off) = hb;
            *(f32x4*)&hout[((size_t)(b0 + b) * SEQ_ + t) * DH_ + dir * H_ + j0] = hv;
        }

        __syncthreads();   // new h visible for next step
    }
}

// ---------------------------------------------------------------------------
// Kernel 7: final logits.  out layout: (B, 2, SEQ)
// ---------------------------------------------------------------------------
__global__ __launch_bounds__(256) void logits_kernel(
    const float* __restrict__ ff, const float* __restrict__ w_sbd,
    const float* __restrict__ b_sbd, float* __restrict__ out)
{
    const int wave = threadIdx.x >> 6, lane = threadIdx.x & 63;
    const int row  = blockIdx.x * 4 + wave;
    const int b    = row >> 7, t = row & 127;
    const float* fr = ff + (size_t)row * DH_;
    float a0 = 0.0f, a1 = 0.0f;
    for (int k = lane; k < DH_; k += 64) {
        const float v = fr[k];
        a0 += v * w_sbd[k];
        a1 += v * w_sbd[DH_ + k];
    }
#pragma unroll
    for (int off = 32; off; off >>= 1) {
        a0 += __shfl_down(a0, off);
        a1 += __shfl_down(a1, off);
    }
    if (lane == 0) {
        out[(size_t)b * 2 * SEQ_ + t]        = a0 + b_sbd[0];
        out[(size_t)b * 2 * SEQ_ + SEQ_ + t] = a1 + b_sbd[1];
    }
}

// ---------------------------------------------------------------------------
extern "C" void kernel_launch(void* const* d_in, const int* in_sizes, int n_in,
                              void* d_out, int out_size, void* d_ws, size_t ws_size,
                              hipStream_t stream)
{
    const float* emb   = (const float*)d_in[0];
    const int*   wid   = (const int*)d_in[1];
    const float* w_ih[4] = {(const float*)d_in[2],  (const float*)d_in[6],
                            (const float*)d_in[10], (const float*)d_in[14]};
    const float* w_hh[4] = {(const float*)d_in[3],  (const float*)d_in[7],
                            (const float*)d_in[11], (const float*)d_in[15]};
    const float* b_ih[4] = {(const float*)d_in[4],  (const float*)d_in[8],
                            (const float*)d_in[12], (const float*)d_in[16]};
    const float* b_hh[4] = {(const float*)d_in[5],  (const float*)d_in[9],
                            (const float*)d_in[13], (const float*)d_in[17]};
    const float* w_ff  = (const float*)d_in[18];
    const float* b_ff  = (const float*)d_in[19];
    const float* w_sbd = (const float*)d_in[20];
    const float* b_sbd = (const float*)d_in[21];
    float* out = (float*)d_out;
    char*  ws  = (char*)d_ws;

    const int M = B_ * SEQ_;   // 32768

    const size_t OFF_R1  = 0;                       // avg/Acat/h pool
    const size_t OFF_XPF = 100663296;
    const size_t OFF_XPB = OFF_XPF + 134217728;
    const size_t OFF_WC  = OFF_XPB + 134217728;     // Wcat pool
    const size_t OFF_WSW = OFF_WC + 17301504;       // swizzled w_hh

    float* avg  = (float*)(ws + OFF_R1);
    unsigned short* Acat = (unsigned short*)(ws + OFF_R1);
    float* xpf  = (float*)(ws + OFF_XPF);
    float* xpb  = (float*)(ws + OFF_XPB);
    float* ffb  = (float*)(ws + OFF_XPF);
    unsigned short* Wc0f = (unsigned short*)(ws + OFF_WC);
    unsigned short* Wc0b = Wc0f + (size_t)1024 * 2304;
    unsigned short* Wc1f = Wc0b + (size_t)1024 * 2304;
    unsigned short* Wc1b = Wc1f + (size_t)1024 * 1536;
    unsigned short* Wcff = Wc1b + (size_t)1024 * 1536;
    short* wsw  = (short*)(ws + OFF_WSW);

    // weight conversions
    wswz_kernel<<<4096, 256, 0, stream>>>(w_hh[0], w_hh[1], w_hh[2], w_hh[3], wsw);
    convw_kernel<<<(1024 * 768 + 255) / 256, 256, 0, stream>>>(w_ih[0], Wc0f, 1024, 768);
    convw_kernel<<<(1024 * 768 + 255) / 256, 256, 0, stream>>>(w_ih[1], Wc0b, 1024, 768);
    convw_kernel<<<(1024 * 512 + 255) / 256, 256, 0, stream>>>(w_ih[2], Wc1f, 1024, 512);
    convw_kernel<<<(1024 * 512 + 255) / 256, 256, 0, stream>>>(w_ih[3], Wc1b, 1024, 512);
    convw_kernel<<<(512 * 512 + 255) / 256, 256, 0, stream>>>(w_ff, Wcff, 512, 512);

    // data path
    scatter_avg_kernel<<<B_, 256, 0, stream>>>(emb, wid, avg);
    convx_kernel<<<M, 256, 0, stream>>>(avg, D_);

    gemm_bf16_kernel<<<dim3(G_ / 128, M / 128), 256, 0, stream>>>(
        Acat, Wc0f, b_ih[0], b_hh[0], xpf, M, G_, D_, 0);
    gemm_bf16_kernel<<<dim3(G_ / 128, M / 128), 256, 0, stream>>>(
        Acat, Wc0b, b_ih[1], b_hh[1], xpb, M, G_, D_, 0);

    lstm_kernel<<<32, 512, 0, stream>>>(xpf, xpb, wsw, wsw + 262144,
                                        (float*)(ws + OFF_R1));

    convx_kernel<<<M, 256, 0, stream>>>((float*)(ws + OFF_R1), DH_);

    gemm_bf16_kernel<<<dim3(G_ / 128, M / 128), 256, 0, stream>>>(
        Acat, Wc1f, b_ih[2], b_hh[2], xpf, M, G_, DH_, 0);
    gemm_bf16_kernel<<<dim3(G_ / 128, M / 128), 256, 0, stream>>>(
        Acat, Wc1b, b_ih[3], b_hh[3], xpb, M, G_, DH_, 0);

    lstm_kernel<<<32, 512, 0, stream>>>(xpf, xpb, wsw + 2 * 262144, wsw + 3 * 262144,
                                        (float*)(ws + OFF_R1));

    convx_kernel<<<M, 256, 0, stream>>>((float*)(ws + OFF_R1), DH_);

    gemm_bf16_kernel<<<dim3(DH_ / 128, M / 128), 256, 0, stream>>>(
        Acat, Wcff, b_ff, nullptr, ffb, M, DH_, DH_, 1);

    logits_kernel<<<M / 4, 256, 0, stream>>>(ffb, w_sbd, b_sbd, out);
}

// Round 7
// 2285.423 us; speedup vs baseline: 3.4990x; 1.1204x over previous
//
#include <hip/hip_runtime.h>
#include <cstddef>

#define B_    256
#define TSUB  192
#define SEQ_  128
#define D_    768
#define H_    256
#define G_    1024   // 4*H
#define DH_   512    // 2*H

typedef __attribute__((ext_vector_type(4))) float f32x4;
typedef __attribute__((ext_vector_type(8))) short bf16x8;
typedef __attribute__((ext_vector_type(4))) unsigned short u16x4;

__device__ __forceinline__ float rcpf_(float x) { return __builtin_amdgcn_rcpf(x); }
__device__ __forceinline__ float sigf_(float x)  { return rcpf_(1.0f + __expf(-x)); }
__device__ __forceinline__ float tanhf_(float x) { return 1.0f - 2.0f * rcpf_(__expf(2.0f * x) + 1.0f); }

__device__ __forceinline__ unsigned short f2bf_(float x) {
    unsigned u = __builtin_bit_cast(unsigned, x);
    return (unsigned short)((u + 0x7fffu + ((u >> 16) & 1u)) >> 16);
}
__device__ __forceinline__ float bf2f_(unsigned short h) {
    return __builtin_bit_cast(float, (unsigned)h << 16);
}
__device__ __forceinline__ void gload_lds16(const void* g, void* l) {
    __builtin_amdgcn_global_load_lds(
        (const __attribute__((address_space(1))) unsigned int*)g,
        (__attribute__((address_space(3))) unsigned int*)l, 16, 0, 0);
}

// ---------------------------------------------------------------------------
// Kernel 1: scatter-average.  One block per batch element.
// ---------------------------------------------------------------------------
__global__ __launch_bounds__(256) void scatter_avg_kernel(
    const float* __restrict__ emb, const int* __restrict__ wid,
    float* __restrict__ avg)
{
    const int b   = blockIdx.x;
    const int tid = threadIdx.x;
    __shared__ int s_wid[TSUB];
    __shared__ int s_start[SEQ_ + 1];

    for (int i = tid; i < TSUB; i += 256) s_wid[i] = wid[b * TSUB + i];
    __syncthreads();
    for (int s = tid; s <= SEQ_; s += 256) {
        int cnt = 0;
        for (int t = 0; t < TSUB; ++t) cnt += (s_wid[t] < s) ? 1 : 0;
        s_start[s] = cnt;
    }
    __syncthreads();

    const float* eb = emb + (size_t)b * TSUB * D_;
    float*       ab = avg + (size_t)b * SEQ_ * D_;
    for (int s = 0; s < SEQ_; ++s) {
        const int st = s_start[s], en = s_start[s + 1];
        const float inv = (en > st) ? 1.0f / (float)(en - st) : 0.0f;
        for (int d = tid; d < D_; d += 256) {
            float sum = 0.0f;
            for (int t = st; t < en; ++t) sum += eb[(size_t)t * D_ + d];
            ab[(size_t)s * D_ + d] = sum * inv;
        }
    }
}

// ---------------------------------------------------------------------------
// Kernel 2: in-place split conversion  f32 X[M][K] -> bf16 [M][2K] = [hi|lo].
// ---------------------------------------------------------------------------
__global__ __launch_bounds__(256) void convx_kernel(float* __restrict__ buf, int K)
{
    __shared__ float row[D_];
    float* r = buf + (size_t)blockIdx.x * K;
    const int tid = threadIdx.x;
    for (int k = tid; k < K; k += 256) row[k] = r[k];
    __syncthreads();
    unsigned short* o = (unsigned short*)r;
    for (int k = tid; k < K; k += 256) {
        const float x = row[k];
        const unsigned short hi = f2bf_(x);
        const float lo = x - bf2f_(hi);
        o[k]     = hi;
        o[K + k] = f2bf_(lo);
    }
}

// ---------------------------------------------------------------------------
// Kernel 3: weight split conversion  f32 W[N][K] -> bf16 Wcat[N][3K]=[hi|lo|hi]
// ---------------------------------------------------------------------------
__global__ __launch_bounds__(256) void convw_kernel(
    const float* __restrict__ W, unsigned short* __restrict__ out, int N, int K)
{
    const int idx = blockIdx.x * 256 + threadIdx.x;
    if (idx >= N * K) return;
    const int n = idx / K, k = idx - n * K;
    const float x = W[idx];
    const unsigned short hi = f2bf_(x);
    const float lo = x - bf2f_(hi);
    const size_t ro = (size_t)n * 3 * K;
    out[ro + k]         = hi;
    out[ro + K + k]     = f2bf_(lo);
    out[ro + 2 * K + k] = hi;
}

// ---------------------------------------------------------------------------
// Kernel 4: bf16 MFMA GEMM (128x128 tile, BK=32, global_load_lds width-16).
// Split precision: C = act( Acat[M][2K]{hi|lo} x Wcat[N][3K]{hi|lo|hi} + b ).
// ---------------------------------------------------------------------------
__global__ __launch_bounds__(256) void gemm_bf16_kernel(
    const unsigned short* __restrict__ A, const unsigned short* __restrict__ Wc,
    const float* __restrict__ b1, const float* __restrict__ b2,
    float* __restrict__ C, int M, int N, int K, int relu)
{
    const int KT = K >> 5;
    const int NT = 3 * KT;
    const int KA = 2 * K, KW = 3 * K;
    const int n0 = blockIdx.x * 128;
    const int m0 = blockIdx.y * 128;
    const int tid  = threadIdx.x;
    const int wv   = tid >> 6;
    const int lane = tid & 63;
    const int lm   = lane & 15, lk = lane >> 4;
    const int wr   = wv >> 1,   wc = wv & 1;

    __shared__ unsigned short As[128 * 32];
    __shared__ unsigned short Bs[128 * 32];

    const int srow  = tid >> 2;
    const int scol8 = (tid & 3) * 8;

    f32x4 acc[4][4];
#pragma unroll
    for (int i = 0; i < 4; ++i)
#pragma unroll
        for (int j = 0; j < 4; ++j) acc[i][j] = (f32x4){0.f, 0.f, 0.f, 0.f};

    for (int kt = 0; kt < NT; ++kt) {
        const int a_kt = (kt < KT) ? kt : kt - KT;
        const unsigned short* Ag = A  + (size_t)(m0 + srow) * KA + a_kt * 32 + scol8;
        const unsigned short* Bg = Wc + (size_t)(n0 + srow) * KW + kt   * 32 + scol8;
        __syncthreads();
        gload_lds16(Ag,                      As + tid * 8);
        gload_lds16(Ag + (size_t)64 * KA,    As + 2048 + tid * 8);
        gload_lds16(Bg,                      Bs + tid * 8);
        gload_lds16(Bg + (size_t)64 * KW,    Bs + 2048 + tid * 8);
        __syncthreads();

        bf16x8 af[4], bfr[4];
#pragma unroll
        for (int mi = 0; mi < 4; ++mi)
            af[mi] = *(const bf16x8*)&As[(wr * 64 + mi * 16 + lm) * 32 + lk * 8];
#pragma unroll
        for (int nj = 0; nj < 4; ++nj)
            bfr[nj] = *(const bf16x8*)&Bs[(wc * 64 + nj * 16 + lm) * 32 + lk * 8];
#pragma unroll
        for (int mi = 0; mi < 4; ++mi)
#pragma unroll
            for (int nj = 0; nj < 4; ++nj)
                acc[mi][nj] = __builtin_amdgcn_mfma_f32_16x16x32_bf16(
                    af[mi], bfr[nj], acc[mi][nj], 0, 0, 0);
    }

#pragma unroll
    for (int mi = 0; mi < 4; ++mi)
#pragma unroll
        for (int nj = 0; nj < 4; ++nj) {
            const int gn = n0 + wc * 64 + nj * 16 + lm;
            const float bias = b1[gn] + (b2 ? b2[gn] : 0.0f);
#pragma unroll
            for (int r = 0; r < 4; ++r) {
                const int gm = m0 + wr * 64 + mi * 16 + lk * 4 + r;
                float v = acc[mi][nj][r] + bias;
                if (relu) v = fmaxf(v, 0.0f);
                C[(size_t)gm * N + gn] = v;
            }
        }
}

// ---------------------------------------------------------------------------
// Kernel 5: swizzle four w_hh (1024x256 f32) into bf16 MFMA A-fragment order
// for the 8-wave LSTM.  [mat][wv 8][kt 8][fr 8][lane 64][e 8]
//   fr = g*2+s:  n = g*256 + wv*32 + s*16 + (lane&15)
//   k  = kt*32 + (lane>>4)*8 + e
// ---------------------------------------------------------------------------
__global__ __launch_bounds__(256) void wswz_kernel(
    const float* __restrict__ w0, const float* __restrict__ w1,
    const float* __restrict__ w2, const float* __restrict__ w3,
    short* __restrict__ out)
{
    const int idx  = blockIdx.x * 256 + threadIdx.x;    // 4*262144
    const int mat  = idx >> 18;
    const int i2   = idx & 262143;
    const int e    = i2 & 7;
    const int l    = (i2 >> 3) & 63;
    const int fr   = (i2 >> 9) & 7;
    const int kt   = (i2 >> 12) & 7;
    const int wv   = (i2 >> 15) & 7;
    const int g    = fr >> 1, s = fr & 1;
    const int n    = g * 256 + wv * 32 + s * 16 + (l & 15);
    const int k    = kt * 32 + ((l >> 4) << 3) + e;
    const float* w = (mat == 0) ? w0 : (mat == 1) ? w1 : (mat == 2) ? w2 : w3;
    out[idx] = (short)f2bf_(w[n * H_ + k]);
}

// ---------------------------------------------------------------------------
// Kernel 6: persistent bidirectional LSTM, bf16 MFMA, WEIGHT-RESIDENT,
// double-buffered h + single LDS-only barrier per step.
// 32 blocks = dir(2) x grp(16), 512 threads = 8 waves (2/SIMD, 256 VGPR cap).
// Wave wv owns j in [32wv,32wv+32) x 4 gates = 64 A-frags (64 KB):
//   kt 0..3 -> registers/AGPRs, kt 4..5 -> LDS (staged once), kt 6..7 -> L2.
// Per-step barrier = `s_waitcnt lgkmcnt(0)` + raw s_barrier (m201 pattern):
// xp prefetch loads and hout stores stay in flight across the barrier.
// ---------------------------------------------------------------------------
__global__ __launch_bounds__(512, 2) void lstm_kernel(
    const float* __restrict__ xpf, const float* __restrict__ xpb,
    const short* __restrict__ wswf, const short* __restrict__ wswb,
    float* __restrict__ hout)
{
    const int dir  = blockIdx.x >> 4;
    const int grp  = blockIdx.x & 15;
    const int tid  = threadIdx.x;
    const int wv   = tid >> 6;          // wave 0..7
    const int lane = tid & 63;
    const int lm   = lane & 15;
    const int lk   = lane >> 4;
    const float* xp  = dir ? xpb : xpf;
    const short* wsw = dir ? wswb : wswf;
    const int b0 = grp * 16;
    const int b  = lm;                  // this lane's batch column

    __shared__ short lds_w[65536];      // 128 KB: [wv 8][kt2 2][fr 8][512]
    __shared__ short h_lds[2][16 * 256];// 2 x 8 KB, [b][k] bf16, XOR-swizzled

    // ---- one-time staging --------------------------------------------------
    for (int i = tid; i < 16 * 256 / 2; i += 512) ((int*)h_lds[0])[i] = 0;
#pragma unroll
    for (int kt2 = 0; kt2 < 2; ++kt2)
#pragma unroll
        for (int fr = 0; fr < 8; ++fr) {
            const short* src = wsw + (((wv * 8 + 4 + kt2) * 8 + fr) << 9) + lane * 8;
            gload_lds16(src, &lds_w[((wv * 2 + kt2) * 8 + fr) << 9]);
        }
    bf16x8 awr[4][8];
#pragma unroll
    for (int kt = 0; kt < 4; ++kt)
#pragma unroll
        for (int fr = 0; fr < 8; ++fr)
            awr[kt][fr] = *(const bf16x8*)(wsw + (((wv * 8 + kt) * 8 + fr) << 9) + lane * 8);

    float c_st[2][4];
#pragma unroll
    for (int s = 0; s < 2; ++s)
#pragma unroll
        for (int r = 0; r < 4; ++r) c_st[s][r] = 0.0f;

    int nof[8];
#pragma unroll
    for (int fr = 0; fr < 8; ++fr)
        nof[fr] = (fr >> 1) * 256 + wv * 32 + (fr & 1) * 16 + lk * 4;

    __syncthreads();   // one-time: full drain ok (gload_lds staging complete)

    // prefetch xp for step 0
    f32x4 xpre[8];
    {
        const int t0 = dir ? (SEQ_ - 1) : 0;
        const float* xr = xp + ((size_t)(b0 + b) * SEQ_ + t0) * G_;
#pragma unroll
        for (int fr = 0; fr < 8; ++fr) xpre[fr] = *(const f32x4*)(xr + nof[fr]);
    }

    int cur = 0;
    for (int step = 0; step < SEQ_; ++step) {
        const int t = dir ? (SEQ_ - 1 - step) : step;
        const char* hr = (const char*)h_lds[0] + cur * 8192;        // read buf
        char*       hw = (char*)h_lds[0] + (cur ^ 1) * 8192;        // write buf

        f32x4 acc[8];
#pragma unroll
        for (int fr = 0; fr < 8; ++fr) acc[fr] = xpre[fr];

        // issue streamed kt=6 loads now (consumed ~2000 cyc later)
        bf16x8 aws6[8];
#pragma unroll
        for (int fr = 0; fr < 8; ++fr)
            aws6[fr] = *(const bf16x8*)(wsw + (((wv * 8 + 6) * 8 + fr) << 9) + lane * 8);

        // kt 0..3: register-resident weights
#pragma unroll
        for (int kt = 0; kt < 4; ++kt) {
            const int off = b * 512 + (((kt * 32 + lk * 8) * 2) ^ ((b & 7) << 4));
            const bf16x8 bh = *(const bf16x8*)(hr + off);
#pragma unroll
            for (int fr = 0; fr < 8; ++fr)
                acc[fr] = __builtin_amdgcn_mfma_f32_16x16x32_bf16(
                    awr[kt][fr], bh, acc[fr], 0, 0, 0);
        }

        // kt 4..5: LDS-resident weights
#pragma unroll
        for (int kt2 = 0; kt2 < 2; ++kt2) {
            const int kt = 4 + kt2;
            const int off = b * 512 + (((kt * 32 + lk * 8) * 2) ^ ((b & 7) << 4));
            const bf16x8 bh = *(const bf16x8*)(hr + off);
            bf16x8 al[8];
#pragma unroll
            for (int fr = 0; fr < 8; ++fr)
                al[fr] = *(const bf16x8*)&lds_w[(((wv * 2 + kt2) * 8 + fr) << 9) + lane * 8];
#pragma unroll
            for (int fr = 0; fr < 8; ++fr)
                acc[fr] = __builtin_amdgcn_mfma_f32_16x16x32_bf16(
                    al[fr], bh, acc[fr], 0, 0, 0);
        }

        // issue streamed kt=7 loads (hidden under kt=6 MFMAs)
        bf16x8 aws7[8];
#pragma unroll
        for (int fr = 0; fr < 8; ++fr)
            aws7[fr] = *(const bf16x8*)(wsw + (((wv * 8 + 7) * 8 + fr) << 9) + lane * 8);

        // kt 6
        {
            const int off = b * 512 + (((6 * 32 + lk * 8) * 2) ^ ((b & 7) << 4));
            const bf16x8 bh = *(const bf16x8*)(hr + off);
#pragma unroll
            for (int fr = 0; fr < 8; ++fr)
                acc[fr] = __builtin_amdgcn_mfma_f32_16x16x32_bf16(
                    aws6[fr], bh, acc[fr], 0, 0, 0);
        }
        // kt 7
        {
            const int off = b * 512 + (((7 * 32 + lk * 8) * 2) ^ ((b & 7) << 4));
            const bf16x8 bh = *(const bf16x8*)(hr + off);
#pragma unroll
            for (int fr = 0; fr < 8; ++fr)
                acc[fr] = __builtin_amdgcn_mfma_f32_16x16x32_bf16(
                    aws7[fr], bh, acc[fr], 0, 0, 0);
        }

        // prefetch xp for next step (in flight across the barrier)
        {
            const int tn = dir ? (t > 0 ? t - 1 : 0) : (t < SEQ_ - 1 ? t + 1 : t);
            const float* xr = xp + ((size_t)(b0 + b) * SEQ_ + tn) * G_;
#pragma unroll
            for (int fr = 0; fr < 8; ++fr) xpre[fr] = *(const f32x4*)(xr + nof[fr]);
        }

        // pointwise: fr = g*2+s  ->  i:acc[s], f:acc[2+s], g:acc[4+s], o:acc[6+s]
#pragma unroll
        for (int s = 0; s < 2; ++s) {
            f32x4 hv;
            u16x4 hb;
#pragma unroll
            for (int r = 0; r < 4; ++r) {
                const float iv = sigf_(acc[s][r]);
                const float fv = sigf_(acc[2 + s][r]);
                const float gv = tanhf_(acc[4 + s][r]);
                const float ov = sigf_(acc[6 + s][r]);
                const float c  = fv * c_st[s][r] + iv * gv;
                c_st[s][r] = c;
                const float h  = ov * tanhf_(c);
                hv[r] = h;
                hb[r] = f2bf_(h);
            }
            const int j0  = wv * 32 + s * 16 + lk * 4;
            const int off = b * 512 + ((j0 * 2) ^ ((b & 7) << 4));
            *(u16x4*)(hw + off) = hb;
            *(f32x4*)&hout[((size_t)(b0 + b) * SEQ_ + t) * DH_ + dir * H_ + j0] = hv;
        }

        // single per-step barrier: LDS-only drain; vmem stays in flight
        asm volatile("s_waitcnt lgkmcnt(0)" ::: "memory");
        __builtin_amdgcn_s_barrier();
        cur ^= 1;
    }
}

// ---------------------------------------------------------------------------
// Kernel 7: final logits.  out layout: (B, 2, SEQ)
// ---------------------------------------------------------------------------
__global__ __launch_bounds__(256) void logits_kernel(
    const float* __restrict__ ff, const float* __restrict__ w_sbd,
    const float* __restrict__ b_sbd, float* __restrict__ out)
{
    const int wave = threadIdx.x >> 6, lane = threadIdx.x & 63;
    const int row  = blockIdx.x * 4 + wave;
    const int b    = row >> 7, t = row & 127;
    const float* fr = ff + (size_t)row * DH_;
    float a0 = 0.0f, a1 = 0.0f;
    for (int k = lane; k < DH_; k += 64) {
        const float v = fr[k];
        a0 += v * w_sbd[k];
        a1 += v * w_sbd[DH_ + k];
    }
#pragma unroll
    for (int off = 32; off; off >>= 1) {
        a0 += __shfl_down(a0, off);
        a1 += __shfl_down(a1, off);
    }
    if (lane == 0) {
        out[(size_t)b * 2 * SEQ_ + t]        = a0 + b_sbd[0];
        out[(size_t)b * 2 * SEQ_ + SEQ_ + t] = a1 + b_sbd[1];
    }
}

// ---------------------------------------------------------------------------
extern "C" void kernel_launch(void* const* d_in, const int* in_sizes, int n_in,
                              void* d_out, int out_size, void* d_ws, size_t ws_size,
                              hipStream_t stream)
{
    const float* emb   = (const float*)d_in[0];
    const int*   wid   = (const int*)d_in[1];
    const float* w_ih[4] = {(const float*)d_in[2],  (const float*)d_in[6],
                            (const float*)d_in[10], (const float*)d_in[14]};
    const float* w_hh[4] = {(const float*)d_in[3],  (const float*)d_in[7],
                            (const float*)d_in[11], (const float*)d_in[15]};
    const float* b_ih[4] = {(const float*)d_in[4],  (const float*)d_in[8],
                            (const float*)d_in[12], (const float*)d_in[16]};
    const float* b_hh[4] = {(const float*)d_in[5],  (const float*)d_in[9],
                            (const float*)d_in[13], (const float*)d_in[17]};
    const float* w_ff  = (const float*)d_in[18];
    const float* b_ff  = (const float*)d_in[19];
    const float* w_sbd = (const float*)d_in[20];
    const float* b_sbd = (const float*)d_in[21];
    float* out = (float*)d_out;
    char*  ws  = (char*)d_ws;

    const int M = B_ * SEQ_;   // 32768

    const size_t OFF_R1  = 0;                       // avg/Acat/h pool
    const size_t OFF_XPF = 100663296;
    const size_t OFF_XPB = OFF_XPF + 134217728;
    const size_t OFF_WC  = OFF_XPB + 134217728;     // Wcat pool
    const size_t OFF_WSW = OFF_WC + 17301504;       // swizzled w_hh

    float* avg  = (float*)(ws + OFF_R1);
    unsigned short* Acat = (unsigned short*)(ws + OFF_R1);
    float* xpf  = (float*)(ws + OFF_XPF);
    float* xpb  = (float*)(ws + OFF_XPB);
    float* ffb  = (float*)(ws + OFF_XPF);
    unsigned short* Wc0f = (unsigned short*)(ws + OFF_WC);
    unsigned short* Wc0b = Wc0f + (size_t)1024 * 2304;
    unsigned short* Wc1f = Wc0b + (size_t)1024 * 2304;
    unsigned short* Wc1b = Wc1f + (size_t)1024 * 1536;
    unsigned short* Wcff = Wc1b + (size_t)1024 * 1536;
    short* wsw  = (short*)(ws + OFF_WSW);

    // weight conversions
    wswz_kernel<<<4096, 256, 0, stream>>>(w_hh[0], w_hh[1], w_hh[2], w_hh[3], wsw);
    convw_kernel<<<(1024 * 768 + 255) / 256, 256, 0, stream>>>(w_ih[0], Wc0f, 1024, 768);
    convw_kernel<<<(1024 * 768 + 255) / 256, 256, 0, stream>>>(w_ih[1], Wc0b, 1024, 768);
    convw_kernel<<<(1024 * 512 + 255) / 256, 256, 0, stream>>>(w_ih[2], Wc1f, 1024, 512);
    convw_kernel<<<(1024 * 512 + 255) / 256, 256, 0, stream>>>(w_ih[3], Wc1b, 1024, 512);
    convw_kernel<<<(512 * 512 + 255) / 256, 256, 0, stream>>>(w_ff, Wcff, 512, 512);

    // data path
    scatter_avg_kernel<<<B_, 256, 0, stream>>>(emb, wid, avg);
    convx_kernel<<<M, 256, 0, stream>>>(avg, D_);

    gemm_bf16_kernel<<<dim3(G_ / 128, M / 128), 256, 0, stream>>>(
        Acat, Wc0f, b_ih[0], b_hh[0], xpf, M, G_, D_, 0);
    gemm_bf16_kernel<<<dim3(G_ / 128, M / 128), 256, 0, stream>>>(
        Acat, Wc0b, b_ih[1], b_hh[1], xpb, M, G_, D_, 0);

    lstm_kernel<<<32, 512, 0, stream>>>(xpf, xpb, wsw, wsw + 262144,
                                        (float*)(ws + OFF_R1));

    convx_kernel<<<M, 256, 0, stream>>>((float*)(ws + OFF_R1), DH_);

    gemm_bf16_kernel<<<dim3(G_ / 128, M / 128), 256, 0, stream>>>(
        Acat, Wc1f, b_ih[2], b_hh[2], xpf, M, G_, DH_, 0);
    gemm_bf16_kernel<<<dim3(G_ / 128, M / 128), 256, 0, stream>>>(
        Acat, Wc1b, b_ih[3], b_hh[3], xpb, M, G_, DH_, 0);

    lstm_kernel<<<32, 512, 0, stream>>>(xpf, xpb, wsw + 2 * 262144, wsw + 3 * 262144,
                                        (float*)(ws + OFF_R1));

    convx_kernel<<<M, 256, 0, stream>>>((float*)(ws + OFF_R1), DH_);

    gemm_bf16_kernel<<<dim3(DH_ / 128, M / 128), 256, 0, stream>>>(
        Acat, Wcff, b_ff, nullptr, ffb, M, DH_, DH_, 1);

    logits_kernel<<<M / 4, 256, 0, stream>>>(ffb, w_sbd, b_sbd, out);
}